// Round 1
// baseline (276.072 us; speedup 1.0000x reference)
//
#include <hip/hip_runtime.h>
#include <hip/hip_bf16.h>
#include <stdint.h>

typedef __bf16 bf16x8 __attribute__((ext_vector_type(8)));
typedef float  f32x4  __attribute__((ext_vector_type(4)));
typedef __hip_bfloat16 bf16;

// Geometry: B=4, Cin=1024, H=50, W=76, Cout=512, 3x3 pad=1; heads 18 + 36.
// M = 4*50*76 = 15200 (pad 15232 = 119*128), N = 512, K = 9*1024 = 9216.
// Padded NHWC features: [4][52][78][1024] bf16 (zero halo).

#define MROWS   15200
#define MTILES  119
#define KSTEPS  144      // 9216 / 64

__device__ __forceinline__ void gload16(const void* g, void* l) {
    // async global->LDS, 16B/lane; LDS dest is wave-uniform base + lane*16
    __builtin_amdgcn_global_load_lds(
        (const __attribute__((address_space(1))) void*)(uintptr_t)g,
        (__attribute__((address_space(3))) void*)(uintptr_t)l,
        16, 0, 0);
}

// ---------------- features NCHW fp32 -> padded NHWC bf16 ----------------
__global__ __launch_bounds__(256) void feat_to_nhwc(const float* __restrict__ src,
                                                    bf16* __restrict__ dst) {
    __shared__ float tile[128][77];            // +1 pad: conflict-free both phases
    const int bid = blockIdx.x;                // ((b*50 + y)*8 + cb)
    const int cb = bid & 7;
    const int by = bid >> 3;
    const int y = by % 50;
    const int b = by / 50;
    const int t = threadIdx.x;

    const float* s = src + (size_t)b * 3891200 + (size_t)(cb * 128) * 3800 + y * 76;
    for (int i = t; i < 128 * 76; i += 256) {
        int ci = i / 76, x = i - ci * 76;
        tile[ci][x] = s[ci * 3800 + x];
    }
    __syncthreads();
    bf16* d = dst + ((size_t)(b * 52 + y + 1) * 78 + 1) * 1024 + cb * 128;
    for (int j = t; j < 76 * 128; j += 256) {
        int x = j >> 7, ci = j & 127;
        d[x * 1024 + ci] = __float2bfloat16(tile[ci][x]);
    }
}

// ---------------- w_feat OIHW fp32 -> [co][(ky,kx,ci)] bf16 ----------------
__global__ __launch_bounds__(256) void wmain_to_bf16(const float* __restrict__ w,
                                                     bf16* __restrict__ w2) {
    int o = blockIdx.x * 256 + threadIdx.x;    // < 512*9216
    int co = o / 9216, r = o - co * 9216;
    int k9 = r >> 10, ci = r & 1023;
    w2[o] = __float2bfloat16(w[(co * 1024 + ci) * 9 + k9]);
}

// ---------------- head weights -> [n(64, pad)][512] bf16 ----------------
__global__ __launch_bounds__(256) void whead_to_bf16(const float* __restrict__ wo,
                                                     const float* __restrict__ wt,
                                                     bf16* __restrict__ wh) {
    int o = blockIdx.x * 256 + threadIdx.x;    // < 64*512
    int n = o >> 9, ci = o & 511;
    float v = 0.f;
    if (n < 18)       v = wo[n * 512 + ci];
    else if (n < 54)  v = wt[(n - 18) * 512 + ci];
    wh[o] = __float2bfloat16(v);
}

// ---------------- conv3x3 implicit GEMM + bias + relu -> h bf16 [m][512] ----------------
__global__ __launch_bounds__(256) void conv_gemm(const bf16* __restrict__ fp,
                                                 const bf16* __restrict__ w2,
                                                 const float* __restrict__ bias,
                                                 bf16* __restrict__ h) {
    __shared__ __attribute__((aligned(16))) bf16 Al[128 * 64];   // [m_local][k] 16KB
    __shared__ __attribute__((aligned(16))) bf16 Bl[128 * 64];   // [n_local][k] 16KB

    const int bid = blockIdx.x;
    const int mt = bid % MTILES;               // m-tile fast -> weight panel L2-hot per XCD
    const int nt = bid / MTILES;
    const int t = threadIdx.x;
    const int lane = t & 63, wv = t >> 6;
    const int wr = wv >> 1, wc = wv & 1;       // wave quadrant (2x2 of 64x64)
    const int kp8 = (t & 7) * 8;               // per-lane k offset in staged 64-chunk

    // staging source pointers (4 rows per matrix per thread)
    const bf16* pA[4];
    const bf16* pB[4];
#pragma unroll
    for (int i = 0; i < 4; ++i) {
        int m = mt * 128 + i * 32 + (t >> 3);
        if (m > MROWS - 1) m = MROWS - 1;      // clamp tail rows (stores predicated)
        int b = m / 3800, r = m - b * 3800;
        int y = r / 76, x = r - y * 76;
        pA[i] = fp + (size_t)((b * 52 + y) * 78 + x) * 1024 + kp8;
        int n = nt * 128 + i * 32 + (t >> 3);
        pB[i] = w2 + (size_t)n * 9216 + kp8;
    }
    char* ldsA = (char*)Al + wv * 1024;
    char* ldsB = (char*)Bl + wv * 1024;

    f32x4 acc[4][4];
#pragma unroll
    for (int i = 0; i < 4; ++i)
#pragma unroll
        for (int j = 0; j < 4; ++j) acc[i][j] = (f32x4){0.f, 0.f, 0.f, 0.f};

    const bf16* aF = Al + (wr * 64 + (lane & 15)) * 64 + (lane >> 4) * 8;
    const bf16* bF = Bl + (wc * 64 + (lane & 15)) * 64 + (lane >> 4) * 8;

    for (int ks = 0; ks < KSTEPS; ++ks) {
        const int ko = ks << 6;
        const int k9 = ko >> 10;               // (ky*3 + kx)
        const int ci0 = ko & 1023;
        const int ky = (k9 * 11) >> 5;         // k9/3 for k9 in [0,9)
        const int kx = k9 - ky * 3;
        const int aoff = ((ky * 78 + kx) << 10) + ci0;
#pragma unroll
        for (int i = 0; i < 4; ++i) gload16(pA[i] + aoff, ldsA + i * 4096);
#pragma unroll
        for (int i = 0; i < 4; ++i) gload16(pB[i] + ko, ldsB + i * 4096);
        __syncthreads();                       // vmcnt(0) drain before barrier

#pragma unroll
        for (int kk = 0; kk < 2; ++kk) {
            bf16x8 av[4], bv[4];
#pragma unroll
            for (int f = 0; f < 4; ++f) av[f] = *(const bf16x8*)(aF + f * 1024 + kk * 32);
#pragma unroll
            for (int f = 0; f < 4; ++f) bv[f] = *(const bf16x8*)(bF + f * 1024 + kk * 32);
#pragma unroll
            for (int fm = 0; fm < 4; ++fm)
#pragma unroll
                for (int fn = 0; fn < 4; ++fn)
                    acc[fm][fn] = __builtin_amdgcn_mfma_f32_16x16x32_bf16(
                        av[fm], bv[fn], acc[fm][fn], 0, 0, 0);
        }
        __syncthreads();                       // protect LDS overwrite next step
    }

    // epilogue: bias + relu -> bf16 h[m][512]
    const int mbase = mt * 128 + wr * 64 + ((lane >> 4) << 2);
    const int nbase = nt * 128 + wc * 64 + (lane & 15);
#pragma unroll
    for (int fn = 0; fn < 4; ++fn) {
        const int n = nbase + fn * 16;
        const float bv = bias[n];
#pragma unroll
        for (int fm = 0; fm < 4; ++fm) {
#pragma unroll
            for (int j = 0; j < 4; ++j) {
                int m = mbase + fm * 16 + j;
                if (m < MROWS) {
                    float v = acc[fm][fn][j] + bv;
                    h[(size_t)m * 512 + n] = __float2bfloat16(v < 0.f ? 0.f : v);
                }
            }
        }
    }
}

// ---------------- 1x1 heads GEMM + bias -> scattered fp32 outputs ----------------
__global__ __launch_bounds__(256) void head_gemm(const bf16* __restrict__ h,
                                                 const bf16* __restrict__ wh,
                                                 const float* __restrict__ bo,
                                                 const float* __restrict__ bt,
                                                 float* __restrict__ out) {
    __shared__ __attribute__((aligned(16))) bf16 Ah[128 * 64];   // [m_local][k-chunk] 16KB
    __shared__ __attribute__((aligned(16))) bf16 Bh[64 * 512];   // whole B resident, 64KB

    const int mt = blockIdx.x;
    const int t = threadIdx.x;
    const int lane = t & 63, wv = t >> 6;
    const int kp8 = (t & 7) * 8;

    {   // preload all head weights: row n = i*4 + wv, full 512-k per wave inst
        char* lb = (char*)Bh + wv * 1024;
        const bf16* src = wh + wv * 512 + (lane) * 8;
#pragma unroll
        for (int i = 0; i < 16; ++i) gload16(src + i * 2048, lb + i * 4096);
    }

    const bf16* pA[4];
#pragma unroll
    for (int i = 0; i < 4; ++i) {
        int m = mt * 128 + i * 32 + (t >> 3);
        if (m > MROWS - 1) m = MROWS - 1;
        pA[i] = h + (size_t)m * 512 + kp8;
    }
    char* la = (char*)Ah + wv * 1024;

    f32x4 acc[2][4];
#pragma unroll
    for (int i = 0; i < 2; ++i)
#pragma unroll
        for (int j = 0; j < 4; ++j) acc[i][j] = (f32x4){0.f, 0.f, 0.f, 0.f};

    const bf16* aF = Ah + (wv * 32 + (lane & 15)) * 64 + (lane >> 4) * 8;
    const bf16* bF = Bh + (lane & 15) * 512 + (lane >> 4) * 8;

    for (int ks = 0; ks < 8; ++ks) {
        const int ko = ks << 6;
#pragma unroll
        for (int i = 0; i < 4; ++i) gload16(pA[i] + ko, la + i * 4096);
        __syncthreads();
#pragma unroll
        for (int kk = 0; kk < 2; ++kk) {
            bf16x8 av[2], bv[4];
#pragma unroll
            for (int f = 0; f < 2; ++f) av[f] = *(const bf16x8*)(aF + f * 1024 + kk * 32);
#pragma unroll
            for (int f = 0; f < 4; ++f) bv[f] = *(const bf16x8*)(bF + f * 8192 + ko + kk * 32);
#pragma unroll
            for (int fm = 0; fm < 2; ++fm)
#pragma unroll
                for (int fn = 0; fn < 4; ++fn)
                    acc[fm][fn] = __builtin_amdgcn_mfma_f32_16x16x32_bf16(
                        av[fm], bv[fn], acc[fm][fn], 0, 0, 0);
        }
        __syncthreads();
    }

    // epilogue: out0[b*68400 + r*18 + n] (n<18), out1 at +273600: [b*136800 + r*36 + n-18]
#pragma unroll
    for (int fn = 0; fn < 4; ++fn) {
        const int n = fn * 16 + (lane & 15);
        if (n >= 54) continue;
        const float bb = (n < 18) ? bo[n] : bt[n - 18];
#pragma unroll
        for (int fm = 0; fm < 2; ++fm) {
#pragma unroll
            for (int j = 0; j < 4; ++j) {
                int m = mt * 128 + wv * 32 + fm * 16 + ((lane >> 4) << 2) + j;
                if (m < MROWS) {
                    int b = m / 3800, r = m - b * 3800;
                    float v = acc[fm][fn][j] + bb;
                    if (n < 18) out[(size_t)b * 68400 + r * 18 + n] = v;
                    else        out[273600 + (size_t)b * 136800 + r * 36 + (n - 18)] = v;
                }
            }
        }
    }
}

extern "C" void kernel_launch(void* const* d_in, const int* in_sizes, int n_in,
                              void* d_out, int out_size, void* d_ws, size_t ws_size,
                              hipStream_t stream) {
    const float* features = (const float*)d_in[0];
    const float* w_feat   = (const float*)d_in[1];
    const float* b_feat   = (const float*)d_in[2];
    const float* w_obj    = (const float*)d_in[3];
    const float* b_obj    = (const float*)d_in[4];
    const float* w_tr     = (const float*)d_in[5];
    const float* b_tr     = (const float*)d_in[6];
    float* out = (float*)d_out;

    char* ws = (char*)d_ws;
    bf16* feat_pad = (bf16*)(ws);              // 4*52*78*1024*2 = 33,226,752 B
    bf16* w2       = (bf16*)(ws + 33226752);   // 512*9216*2     =  9,437,184 B
    bf16* wh       = (bf16*)(ws + 42663936);   // 64*512*2       =     65,536 B
    bf16* hbuf     = (bf16*)(ws + 42729472);   // 15232*512*2    = 15,597,568 B  (total 58.3 MB)

    hipMemsetAsync(feat_pad, 0, 33226752, stream);                   // zero halo
    feat_to_nhwc<<<dim3(1600), dim3(256), 0, stream>>>(features, feat_pad);
    wmain_to_bf16<<<dim3(18432), dim3(256), 0, stream>>>(w_feat, w2);
    whead_to_bf16<<<dim3(128), dim3(256), 0, stream>>>(w_obj, w_tr, wh);
    conv_gemm<<<dim3(MTILES * 4), dim3(256), 0, stream>>>(feat_pad, w2, b_feat, hbuf);
    head_gemm<<<dim3(MTILES), dim3(256), 0, stream>>>(hbuf, wh, b_obj, b_tr, out);
}